// Round 2
// baseline (42431.668 us; speedup 1.0000x reference)
//
#include <hip/hip_runtime.h>
#include <hip/hip_fp16.h>

// LSTM autoencoder B=64,S=256,D=H=1024,L=2 — persistent-kernel version.
// 256 blocks (1/CU, forced by 128KB LDS), 512 thr = 8 waves.
// block = (layer, j-strip of 8): holds [32 gate-cols x 2048 K] f16 weights in LDS.
// 2 segments (enc, dec) x 257 pipelined phases; hand-rolled grid barrier per phase.
// c-state in registers for the whole kernel; h-state ping-pong f16 in global.

#define NBLK 256
#define NTHR 512
#define LDS_BYTES (128 * 1024)

typedef _Float16 half8 __attribute__((ext_vector_type(8)));
typedef float    f32x4 __attribute__((ext_vector_type(4)));

__device__ __forceinline__ float sigm_(float x) { return 1.f / (1.f + __expf(-x)); }
__device__ __forceinline__ float tanh_(float x) {
  float e = __expf(-2.f * fabsf(x));
  float r = (1.f - e) / (1.f + e);
  return x >= 0.f ? r : -r;
}

__global__ __launch_bounds__(256) void cvt_x(const float* __restrict__ src,
                                             __half* __restrict__ dst, int n) {
  int i = blockIdx.x * 256 + threadIdx.x;
  if (i < n) dst[i] = __float2half(src[i]);
}

// Build K-concat weight matrix: dst[n][k], k<1024 from wa (optionally col-flipped), else wb.
__global__ __launch_bounds__(256) void cvt_wcat(const float* __restrict__ wa,
                                                const float* __restrict__ wb,
                                                __half* __restrict__ dst, int flipA) {
  int i = blockIdx.x * 256 + threadIdx.x;  // over 4096*2048
  if (i >= 4096 * 2048) return;
  int n = i >> 11, k = i & 2047;
  float v = (k < 1024) ? wa[n * 1024 + (flipA ? (1023 - k) : k)]
                       : wb[n * 1024 + (k - 1024)];
  dst[i] = __float2half(v);
}

__global__ void fail_mark(float* out) { out[0] = 1.0e9f; }

__global__ __launch_bounds__(512) void lstm_persist(
    const __half* __restrict__ xf16,
    const __half* __restrict__ We0, const __half* __restrict__ We1,
    const __half* __restrict__ Wd0, const __half* __restrict__ Wd1,
    const float* __restrict__ ebi0, const float* __restrict__ ebh0,
    const float* __restrict__ ebi1, const float* __restrict__ ebh1,
    const float* __restrict__ dbi0, const float* __restrict__ dbh0,
    const float* __restrict__ dbi1, const float* __restrict__ dbh1,
    __half* __restrict__ h0p0, __half* __restrict__ h0p1,
    __half* __restrict__ h1p0, __half* __restrict__ h1p1,
    __half* __restrict__ femb, float* __restrict__ out,
    unsigned* __restrict__ ctr) {
  extern __shared__ __half lds[];
  const int tid   = threadIdx.x, lane = tid & 63, w = tid >> 6;
  const int layer = blockIdx.x >> 7;   // 128 blocks layer0, 128 layer1
  const int jb    = blockIdx.x & 127;  // j-strip base jb*8
  const int mtile = w >> 1, nt = w & 1;
  const int c4 = lane & 15, kq = lane >> 4;
  const int gi = c4 >> 2;              // this lane's gate index (i,f,g,o)
  const int arow = mtile * 16 + c4;    // A-frag row
  const int ldscol = nt * 16 + c4;     // LDS B column (0..31)
  __half* h0buf[2] = {h0p0, h0p1};
  __half* h1buf[2] = {h1p0, h1p1};

  f32x4 c = {0.f, 0.f, 0.f, 0.f};      // cell state lives in registers enc->dec
  unsigned tgt = 0;

  for (int seg = 0; seg < 2; ++seg) {
    // ---- stage this block's [32 x 2048] f16 weight slice into LDS ----
    const __half* W = (seg == 0) ? (layer ? We1 : We0) : (layer ? Wd1 : Wd0);
    #pragma unroll
    for (int i = 0; i < 16; ++i) {
      int flat = i * 512 + tid;            // 8192 chunks of 16B
      int cc = flat >> 8, kk = flat & 255; // LDS col, k-chunk
      int cc4 = cc & 15, ct = cc >> 4;
      int n = (cc4 >> 2) * 1024 + jb * 8 + ct * 4 + (cc4 & 3);
      *(half8*)(lds + ((size_t)kk * 32 + cc) * 8) =
          *(const half8*)(W + (size_t)n * 2048 + (size_t)kk * 8);
    }
    const float* bi = (seg == 0) ? (layer ? ebi1 : ebi0) : (layer ? dbi1 : dbi0);
    const float* bh = (seg == 0) ? (layer ? ebh1 : ebh0) : (layer ? dbh1 : dbh0);
    const int nlane = gi * 1024 + jb * 8 + nt * 4 + (lane & 3);
    const float bb = bi[nlane] + bh[nlane];
    __syncthreads();

    for (int p = 0; p <= 256; ++p) {
      const int active = (layer == 0) ? (p <= 255) : (p >= 1);
      if (active) {
        const __half* s1 = (layer == 0) ? h0buf[p & 1] : h1buf[(p + 1) & 1];
        const __half* s0;
        long long st0;
        if (layer == 0) {
          if (seg == 0)      { s0 = xf16 + (size_t)p * 1024;      st0 = 262144; }
          else if (p == 0)   { s0 = femb;                          st0 = 1024; }
          else               { s0 = xf16 + (size_t)(p - 1) * 1024; st0 = 262144; }
        } else             { s0 = h0buf[p & 1];                    st0 = 1024; }

        const __half* a0 = s0 + (long long)arow * st0 + kq * 8;
        const __half* a1 = s1 + (long long)arow * 1024 + kq * 8;
        const __half* b0 = lds + ((size_t)kq * 32 + ldscol) * 8;
        f32x4 acc = {0.f, 0.f, 0.f, 0.f};
        #pragma unroll 8
        for (int ks = 0; ks < 32; ++ks) {
          half8 av = *(const half8*)(a0 + ks * 32);
          half8 bv = *(const half8*)(b0 + (size_t)ks * 1024);  // 4*32*8
          acc = __builtin_amdgcn_mfma_f32_16x16x32_f16(av, bv, acc, 0, 0, 0);
        }
        const __half* b1 = b0 + (size_t)128 * 32 * 8;
        #pragma unroll 8
        for (int ks = 0; ks < 32; ++ks) {
          half8 av = *(const half8*)(a1 + ks * 32);
          half8 bv = *(const half8*)(b1 + (size_t)ks * 1024);
          acc = __builtin_amdgcn_mfma_f32_16x16x32_f16(av, bv, acc, 0, 0, 0);
        }

        __half* hdst = (layer == 0) ? h0buf[(p + 1) & 1] : h1buf[p & 1];
        const int j = jb * 8 + nt * 4 + (lane & 3);
        #pragma unroll
        for (int r = 0; r < 4; ++r) {
          float v = acc[r] + bb;
          // allgather the 4 gates across the 4-lane gate group (xor 4, 8)
          float vx4  = __shfl_xor(v, 4);
          float vx8  = __shfl_xor(v, 8);
          float vx12 = __shfl_xor(vx4, 8);
          float vi = gi == 0 ? v    : gi == 1 ? vx4  : gi == 2 ? vx8  : vx12;
          float vf = gi == 0 ? vx4  : gi == 1 ? v    : gi == 2 ? vx12 : vx8;
          float vg = gi == 0 ? vx8  : gi == 1 ? vx12 : gi == 2 ? v    : vx4;
          float vo = gi == 0 ? vx12 : gi == 1 ? vx8  : gi == 2 ? vx4  : v;
          float cn = sigm_(vf) * c[r] + sigm_(vi) * tanh_(vg);
          c[r] = cn;
          float h = sigm_(vo) * tanh_(cn);
          if (gi == 0) {
            const int b = mtile * 16 + kq * 4 + r;  // C/D row (m89 layout)
            hdst[(size_t)b * 1024 + j] = __float2half(h);
            if (layer == 1) {
              if (seg == 0) {
                if (p == 256) {
                  out[(size_t)b * 1024 + j] = h;                       // emb
                  femb[(size_t)b * 1024 + (1023 - j)] = __float2half(h); // flipped emb
                }
              } else {
                out[65536 + ((size_t)b * 256 + (p - 1)) * 1024 + (1023 - j)] = h;
              }
            }
          }
        }
      }

      // ---- grid barrier (device-scope, sense-free monotonic counter) ----
      tgt += NBLK;
      __syncthreads();
      __threadfence();  // release: flush this XCD's writes to coherent point
      if (tid == 0) {
        __hip_atomic_fetch_add(ctr, 1u, __ATOMIC_RELAXED, __HIP_MEMORY_SCOPE_AGENT);
        int guard = 0;
        while (__hip_atomic_load(ctr, __ATOMIC_RELAXED, __HIP_MEMORY_SCOPE_AGENT) < tgt) {
          __builtin_amdgcn_s_sleep(2);
          if (++guard > (1 << 22)) break;  // deadlock safety: break (results wrong, no hang)
        }
      }
      __syncthreads();
      __threadfence();  // acquire: invalidate stale cached lines before next phase's loads
    }
  }
}

extern "C" void kernel_launch(void* const* d_in, const int* in_sizes, int n_in,
                              void* d_out, int out_size, void* d_ws, size_t ws_size,
                              hipStream_t stream) {
  const float* x     = (const float*)d_in[0];
  const float* eWih0 = (const float*)d_in[1];
  const float* eWhh0 = (const float*)d_in[2];
  const float* ebih0 = (const float*)d_in[3];
  const float* ebhh0 = (const float*)d_in[4];
  const float* eWih1 = (const float*)d_in[5];
  const float* eWhh1 = (const float*)d_in[6];
  const float* ebih1 = (const float*)d_in[7];
  const float* ebhh1 = (const float*)d_in[8];
  const float* dWih0 = (const float*)d_in[9];
  const float* dWhh0 = (const float*)d_in[10];
  const float* dbih0 = (const float*)d_in[11];
  const float* dbhh0 = (const float*)d_in[12];
  const float* dWih1 = (const float*)d_in[13];
  const float* dWhh1 = (const float*)d_in[14];
  const float* dbih1 = (const float*)d_in[15];
  const float* dbhh1 = (const float*)d_in[16];
  float* out = (float*)d_out;

  char* ws = (char*)d_ws;
  size_t off = 0;
  auto alloc = [&](size_t bytes) { char* p = ws + off; off += (bytes + 255) & ~(size_t)255; return p; };
  const size_t WCB = (size_t)4096 * 2048 * sizeof(__half);  // 16MB
  __half* xf16 = (__half*)alloc((size_t)64 * 256 * 1024 * sizeof(__half));  // 32MB
  __half* We0  = (__half*)alloc(WCB);
  __half* We1  = (__half*)alloc(WCB);
  __half* Wd0  = (__half*)alloc(WCB);
  __half* Wd1  = (__half*)alloc(WCB);
  __half* h0p0 = (__half*)alloc((size_t)64 * 1024 * sizeof(__half));
  __half* h0p1 = (__half*)alloc((size_t)64 * 1024 * sizeof(__half));
  __half* h1p0 = (__half*)alloc((size_t)64 * 1024 * sizeof(__half));
  __half* h1p1 = (__half*)alloc((size_t)64 * 1024 * sizeof(__half));
  __half* femb = (__half*)alloc((size_t)64 * 1024 * sizeof(__half));
  unsigned* ctr = (unsigned*)alloc(256);

  if (ws_size < off) {
    hipLaunchKernelGGL(fail_mark, dim3(1), dim3(1), 0, stream, out);
    return;
  }

  // conversions (graph-captured, rerun every replay; deterministic)
  const int xn = 64 * 256 * 1024;
  cvt_x<<<(xn + 255) / 256, 256, 0, stream>>>(x, xf16, xn);
  const int wg = (4096 * 2048 + 255) / 256;
  cvt_wcat<<<wg, 256, 0, stream>>>(eWih0, eWhh0, We0, 0);
  cvt_wcat<<<wg, 256, 0, stream>>>(eWih1, eWhh1, We1, 0);
  cvt_wcat<<<wg, 256, 0, stream>>>(dWih0, dWhh0, Wd0, 1);  // flipped input-cols
  cvt_wcat<<<wg, 256, 0, stream>>>(dWih1, dWhh1, Wd1, 0);

  hipMemsetAsync(h0p0, 0, (size_t)64 * 1024 * 2, stream);
  hipMemsetAsync(h0p1, 0, (size_t)64 * 1024 * 2, stream);
  hipMemsetAsync(h1p0, 0, (size_t)64 * 1024 * 2, stream);
  hipMemsetAsync(h1p1, 0, (size_t)64 * 1024 * 2, stream);
  hipMemsetAsync(ctr, 0, 256, stream);

  hipFuncSetAttribute((const void*)lstm_persist,
                      hipFuncAttributeMaxDynamicSharedMemorySize, LDS_BYTES);
  lstm_persist<<<NBLK, NTHR, LDS_BYTES, stream>>>(
      xf16, We0, We1, Wd0, Wd1,
      ebih0, ebhh0, ebih1, ebhh1, dbih0, dbhh0, dbih1, dbhh1,
      h0p0, h0p1, h1p0, h1p1, femb, out, ctr);
}

// Round 4
// 9713.972 us; speedup vs baseline: 4.3681x; 4.3681x over previous
//
#include <hip/hip_runtime.h>
#include <hip/hip_fp16.h>

// LSTM autoencoder B=64,S=256,D=H=1024,L=2 — persistent kernel, round 4.
// = round 3 design with two bug fixes:
//  (1) early-clobber ("=&v") on ALL inline-asm async-load outputs — r3's "=v"
//      let the allocator alias load dests with the address pair -> GPU fault.
//  (2) h ping-pong pointers via ternary selects, not runtime-indexed local
//      arrays (rule #20: those go to scratch and pollute vmcnt counting).
// Coherence: h/femb via sc0 sc1 (device-coherent, L2-bypass) loads/stores,
// drained with vmcnt(0) before the barrier arrive. No __threadfence anywhere.

#define NBLK 256
#define NTHR 512
#define LDS_BYTES (128 * 1024)

typedef _Float16 half8 __attribute__((ext_vector_type(8)));
typedef float    f32x4 __attribute__((ext_vector_type(4)));

__device__ __forceinline__ float sigm_(float x) { return 1.f / (1.f + __expf(-x)); }
__device__ __forceinline__ float tanh_(float x) {
  float e = __expf(-2.f * fabsf(x));
  float r = (1.f - e) / (1.f + e);
  return x >= 0.f ? r : -r;
}

__global__ __launch_bounds__(256) void cvt_x(const float* __restrict__ src,
                                             __half* __restrict__ dst, int n) {
  int i = blockIdx.x * 256 + threadIdx.x;
  if (i < n) dst[i] = __float2half(src[i]);
}

__global__ __launch_bounds__(256) void cvt_wcat(const float* __restrict__ wa,
                                                const float* __restrict__ wb,
                                                __half* __restrict__ dst, int flipA) {
  int i = blockIdx.x * 256 + threadIdx.x;  // over 4096*2048
  if (i >= 4096 * 2048) return;
  int n = i >> 11, k = i & 2047;
  float v = (k < 1024) ? wa[n * 1024 + (flipA ? (1023 - k) : k)]
                       : wb[n * 1024 + (k - 1024)];
  dst[i] = __float2half(v);
}

__global__ void fail_mark(float* out) { out[0] = 1.0e9f; }

// ---- async 8x16B load issue; outputs EARLY-CLOBBER so none alias the addr pair ----
__device__ __forceinline__ void issue8c(const __half* p,
    half8& r0, half8& r1, half8& r2, half8& r3,
    half8& r4, half8& r5, half8& r6, half8& r7) {
  asm volatile(
    "global_load_dwordx4 %0, %8, off sc0 sc1\n\t"
    "global_load_dwordx4 %1, %8, off offset:64 sc0 sc1\n\t"
    "global_load_dwordx4 %2, %8, off offset:128 sc0 sc1\n\t"
    "global_load_dwordx4 %3, %8, off offset:192 sc0 sc1\n\t"
    "global_load_dwordx4 %4, %8, off offset:256 sc0 sc1\n\t"
    "global_load_dwordx4 %5, %8, off offset:320 sc0 sc1\n\t"
    "global_load_dwordx4 %6, %8, off offset:384 sc0 sc1\n\t"
    "global_load_dwordx4 %7, %8, off offset:448 sc0 sc1"
    : "=&v"(r0), "=&v"(r1), "=&v"(r2), "=&v"(r3),
      "=&v"(r4), "=&v"(r5), "=&v"(r6), "=&v"(r7)
    : "v"(p) : "memory");
}
__device__ __forceinline__ void issue8p(const __half* p,
    half8& r0, half8& r1, half8& r2, half8& r3,
    half8& r4, half8& r5, half8& r6, half8& r7) {
  asm volatile(
    "global_load_dwordx4 %0, %8, off\n\t"
    "global_load_dwordx4 %1, %8, off offset:64\n\t"
    "global_load_dwordx4 %2, %8, off offset:128\n\t"
    "global_load_dwordx4 %3, %8, off offset:192\n\t"
    "global_load_dwordx4 %4, %8, off offset:256\n\t"
    "global_load_dwordx4 %5, %8, off offset:320\n\t"
    "global_load_dwordx4 %6, %8, off offset:384\n\t"
    "global_load_dwordx4 %7, %8, off offset:448"
    : "=&v"(r0), "=&v"(r1), "=&v"(r2), "=&v"(r3),
      "=&v"(r4), "=&v"(r5), "=&v"(r6), "=&v"(r7)
    : "v"(p) : "memory");
}

__device__ __forceinline__ void st2_coh(__half* p, float h) {
  unsigned v = (unsigned)__half_as_ushort(__float2half(h));
  asm volatile("global_store_short %0, %1, off sc0 sc1" :: "v"(p), "v"(v) : "memory");
}

__device__ __forceinline__ unsigned poll8(const unsigned* c) {
  unsigned a0, a1, a2, a3, a4, a5, a6, a7;
  asm volatile(
    "global_load_dword %0, %8, off sc0 sc1\n\t"
    "global_load_dword %1, %8, off offset:64 sc0 sc1\n\t"
    "global_load_dword %2, %8, off offset:128 sc0 sc1\n\t"
    "global_load_dword %3, %8, off offset:192 sc0 sc1\n\t"
    "global_load_dword %4, %8, off offset:256 sc0 sc1\n\t"
    "global_load_dword %5, %8, off offset:320 sc0 sc1\n\t"
    "global_load_dword %6, %8, off offset:384 sc0 sc1\n\t"
    "global_load_dword %7, %8, off offset:448 sc0 sc1\n\t"
    "s_waitcnt vmcnt(0)"
    : "=&v"(a0), "=&v"(a1), "=&v"(a2), "=&v"(a3),
      "=&v"(a4), "=&v"(a5), "=&v"(a6), "=&v"(a7)
    : "v"(c) : "memory");
  return a0 + a1 + a2 + a3 + a4 + a5 + a6 + a7;
}

#define WAITVM(n) do { asm volatile("s_waitcnt vmcnt(" #n ")" ::: "memory"); \
                       __builtin_amdgcn_sched_barrier(0); } while (0)
#define BANK(X) X##0, X##1, X##2, X##3, X##4, X##5, X##6, X##7
#define ISSUE(X, c) do { const __half* _p = ((c) < 4 ? pa + (c) * 256 : pb + ((c) - 4) * 256); \
                         if ((c) < 4 ? coh0 : 1) issue8c(_p, BANK(X)); \
                         else issue8p(_p, BANK(X)); } while (0)
#define MFMA8(X, c) do { const __half* _b = ldsb + (c) * 8192; \
  acc = __builtin_amdgcn_mfma_f32_16x16x32_f16(X##0, *(const half8*)(_b + 0 * 1024), acc, 0, 0, 0); \
  acc = __builtin_amdgcn_mfma_f32_16x16x32_f16(X##1, *(const half8*)(_b + 1 * 1024), acc, 0, 0, 0); \
  acc = __builtin_amdgcn_mfma_f32_16x16x32_f16(X##2, *(const half8*)(_b + 2 * 1024), acc, 0, 0, 0); \
  acc = __builtin_amdgcn_mfma_f32_16x16x32_f16(X##3, *(const half8*)(_b + 3 * 1024), acc, 0, 0, 0); \
  acc = __builtin_amdgcn_mfma_f32_16x16x32_f16(X##4, *(const half8*)(_b + 4 * 1024), acc, 0, 0, 0); \
  acc = __builtin_amdgcn_mfma_f32_16x16x32_f16(X##5, *(const half8*)(_b + 5 * 1024), acc, 0, 0, 0); \
  acc = __builtin_amdgcn_mfma_f32_16x16x32_f16(X##6, *(const half8*)(_b + 6 * 1024), acc, 0, 0, 0); \
  acc = __builtin_amdgcn_mfma_f32_16x16x32_f16(X##7, *(const half8*)(_b + 7 * 1024), acc, 0, 0, 0); } while (0)

__global__ __launch_bounds__(512) void lstm_persist(
    const __half* __restrict__ xf16,
    const __half* __restrict__ We0, const __half* __restrict__ We1,
    const __half* __restrict__ Wd0, const __half* __restrict__ Wd1,
    const float* __restrict__ ebi0, const float* __restrict__ ebh0,
    const float* __restrict__ ebi1, const float* __restrict__ ebh1,
    const float* __restrict__ dbi0, const float* __restrict__ dbh0,
    const float* __restrict__ dbi1, const float* __restrict__ dbh1,
    __half* __restrict__ h0p0, __half* __restrict__ h0p1,
    __half* __restrict__ h1p0, __half* __restrict__ h1p1,
    __half* __restrict__ femb, float* __restrict__ out,
    unsigned* __restrict__ ctr) {
  extern __shared__ __half lds[];
  const int tid   = threadIdx.x, lane = tid & 63, w = tid >> 6;
  const int layer = blockIdx.x >> 7;
  const int jb    = blockIdx.x & 127;
  const int mtile = w >> 1, nt = w & 1;
  const int c4 = lane & 15, kq = lane >> 4;
  const int gi = c4 >> 2;
  const int arow = mtile * 16 + c4;
  const int ldscol = nt * 16 + c4;
  unsigned* myctr = ctr + (blockIdx.x & 7) * 16;  // 64B apart

  f32x4 c = {0.f, 0.f, 0.f, 0.f};
  unsigned tgt = 0;

  for (int seg = 0; seg < 2; ++seg) {
    const __half* W = (seg == 0) ? (layer ? We1 : We0) : (layer ? Wd1 : Wd0);
    #pragma unroll
    for (int i = 0; i < 16; ++i) {
      int flat = i * 512 + tid;
      int cc = flat >> 8, kk = flat & 255;
      int cc4 = cc & 15, ct = cc >> 4;
      int n = (cc4 >> 2) * 1024 + jb * 8 + ct * 4 + (cc4 & 3);
      *(half8*)(lds + ((size_t)kk * 32 + cc) * 8) =
          *(const half8*)(W + (size_t)n * 2048 + (size_t)kk * 8);
    }
    const float* bi = (seg == 0) ? (layer ? ebi1 : ebi0) : (layer ? dbi1 : dbi0);
    const float* bh = (seg == 0) ? (layer ? ebh1 : ebh0) : (layer ? dbh1 : dbh0);
    const int nlane = gi * 1024 + jb * 8 + nt * 4 + (lane & 3);
    const float bb = bi[nlane] + bh[nlane];
    __syncthreads();
    asm volatile("s_waitcnt vmcnt(0)" ::: "memory");  // clean vmcnt before counted phases

    const __half* ldsb = lds + ((size_t)kq * 32 + ldscol) * 8;

    for (int p = 0; p <= 256; ++p) {
      // h ping-pong via ternary selects (SGPR cselect, NO scratch arrays)
      const __half* h0rd = (p & 1) ? h0p1 : h0p0;   // h0buf[p&1]
      __half*       h0wr = (p & 1) ? h0p0 : h0p1;   // h0buf[(p+1)&1]
      const __half* h1rd = (p & 1) ? h1p0 : h1p1;   // h1buf[(p+1)&1]
      __half*       h1wr = (p & 1) ? h1p1 : h1p0;   // h1buf[p&1]
      const int active = (layer == 0) ? (p <= 255) : (p >= 1);
      if (active) {
        const __half* s1 = (layer == 0) ? h0rd : h1rd;
        const __half* s0;
        long long st0;
        int coh0;
        if (layer == 0) {
          if (seg == 0)      { s0 = xf16 + (size_t)p * 1024;       st0 = 262144; coh0 = 0; }
          else if (p == 0)   { s0 = femb;                          st0 = 1024;   coh0 = 1; }
          else               { s0 = xf16 + (size_t)(p - 1) * 1024; st0 = 262144; coh0 = 0; }
        } else             { s0 = h0rd;                            st0 = 1024;   coh0 = 1; }

        const __half* pa = s0 + (long long)arow * st0 + kq * 8;
        const __half* pb = s1 + (long long)arow * 1024 + kq * 8;
        f32x4 acc = {0.f, 0.f, 0.f, 0.f};
        half8 A0,A1,A2,A3,A4,A5,A6,A7, B0,B1,B2,B3,B4,B5,B6,B7, C0,C1,C2,C3,C4,C5,C6,C7;

        // 8 chunks (0-3: s0, 4-7: s1), 3 banks in flight, counted vmcnt
        ISSUE(A, 0); ISSUE(B, 1); ISSUE(C, 2);
        WAITVM(16); MFMA8(A, 0); ISSUE(A, 3);
        WAITVM(16); MFMA8(B, 1); ISSUE(B, 4);
        WAITVM(16); MFMA8(C, 2); ISSUE(C, 5);
        WAITVM(16); MFMA8(A, 3); ISSUE(A, 6);
        WAITVM(16); MFMA8(B, 4); ISSUE(B, 7);
        WAITVM(16); MFMA8(C, 5);
        WAITVM(8);  MFMA8(A, 6);
        WAITVM(0);  MFMA8(B, 7);

        __half* hdst = (layer == 0) ? h0wr : h1wr;
        const int j = jb * 8 + nt * 4 + (lane & 3);
        #pragma unroll
        for (int r = 0; r < 4; ++r) {
          float v = acc[r] + bb;
          float vx4  = __shfl_xor(v, 4);
          float vx8  = __shfl_xor(v, 8);
          float vx12 = __shfl_xor(vx4, 8);
          float vi = gi == 0 ? v    : gi == 1 ? vx4  : gi == 2 ? vx8  : vx12;
          float vf = gi == 0 ? vx4  : gi == 1 ? v    : gi == 2 ? vx12 : vx8;
          float vg = gi == 0 ? vx8  : gi == 1 ? vx12 : gi == 2 ? v    : vx4;
          float vo = gi == 0 ? vx12 : gi == 1 ? vx8  : gi == 2 ? vx4  : v;
          float cn = sigm_(vf) * c[r] + sigm_(vi) * tanh_(vg);
          c[r] = cn;
          float h = sigm_(vo) * tanh_(cn);
          if (gi == 0) {
            const int b = mtile * 16 + kq * 4 + r;  // C/D row (m89 layout)
            st2_coh(hdst + (size_t)b * 1024 + j, h);
            if (layer == 1) {
              if (seg == 0) {
                if (p == 256) {
                  out[(size_t)b * 1024 + j] = h;                 // emb (plain)
                  st2_coh(femb + (size_t)b * 1024 + (1023 - j), h);
                }
              } else {
                out[65536 + ((size_t)b * 256 + (p - 1)) * 1024 + (1023 - j)] = h;
              }
            }
          }
        }
      }

      // ---- grid barrier: drain coherent stores, arrive on spread counters, poll ----
      tgt += NBLK;
      asm volatile("s_waitcnt vmcnt(0)" ::: "memory");
      __syncthreads();
      if (tid == 0) {
        __hip_atomic_fetch_add(myctr, 1u, __ATOMIC_RELAXED, __HIP_MEMORY_SCOPE_AGENT);
        int guard = 0;
        while (poll8(ctr) < tgt) {
          __builtin_amdgcn_s_sleep(1);
          if (++guard > (1 << 18)) break;  // hang safety: break (wrong results, no hang)
        }
      }
      __syncthreads();
    }
  }
}

extern "C" void kernel_launch(void* const* d_in, const int* in_sizes, int n_in,
                              void* d_out, int out_size, void* d_ws, size_t ws_size,
                              hipStream_t stream) {
  const float* x     = (const float*)d_in[0];
  const float* eWih0 = (const float*)d_in[1];
  const float* eWhh0 = (const float*)d_in[2];
  const float* ebih0 = (const float*)d_in[3];
  const float* ebhh0 = (const float*)d_in[4];
  const float* eWih1 = (const float*)d_in[5];
  const float* eWhh1 = (const float*)d_in[6];
  const float* ebih1 = (const float*)d_in[7];
  const float* ebhh1 = (const float*)d_in[8];
  const float* dWih0 = (const float*)d_in[9];
  const float* dWhh0 = (const float*)d_in[10];
  const float* dbih0 = (const float*)d_in[11];
  const float* dbhh0 = (const float*)d_in[12];
  const float* dWih1 = (const float*)d_in[13];
  const float* dWhh1 = (const float*)d_in[14];
  const float* dbih1 = (const float*)d_in[15];
  const float* dbhh1 = (const float*)d_in[16];
  float* out = (float*)d_out;

  char* ws = (char*)d_ws;
  size_t off = 0;
  auto alloc = [&](size_t bytes) { char* p = ws + off; off += (bytes + 255) & ~(size_t)255; return p; };
  const size_t WCB = (size_t)4096 * 2048 * sizeof(__half);  // 16MB
  __half* xf16 = (__half*)alloc((size_t)64 * 256 * 1024 * sizeof(__half));  // 32MB
  __half* We0  = (__half*)alloc(WCB);
  __half* We1  = (__half*)alloc(WCB);
  __half* Wd0  = (__half*)alloc(WCB);
  __half* Wd1  = (__half*)alloc(WCB);
  __half* h0p0 = (__half*)alloc((size_t)64 * 1024 * sizeof(__half));
  __half* h0p1 = (__half*)alloc((size_t)64 * 1024 * sizeof(__half));
  __half* h1p0 = (__half*)alloc((size_t)64 * 1024 * sizeof(__half));
  __half* h1p1 = (__half*)alloc((size_t)64 * 1024 * sizeof(__half));
  __half* femb = (__half*)alloc((size_t)64 * 1024 * sizeof(__half));
  unsigned* ctr = (unsigned*)alloc(1024);

  if (ws_size < off) {
    hipLaunchKernelGGL(fail_mark, dim3(1), dim3(1), 0, stream, out);
    return;
  }

  const int xn = 64 * 256 * 1024;
  cvt_x<<<(xn + 255) / 256, 256, 0, stream>>>(x, xf16, xn);
  const int wg = (4096 * 2048 + 255) / 256;
  cvt_wcat<<<wg, 256, 0, stream>>>(eWih0, eWhh0, We0, 0);
  cvt_wcat<<<wg, 256, 0, stream>>>(eWih1, eWhh1, We1, 0);
  cvt_wcat<<<wg, 256, 0, stream>>>(dWih0, dWhh0, Wd0, 1);  // flipped input-cols
  cvt_wcat<<<wg, 256, 0, stream>>>(dWih1, dWhh1, Wd1, 0);

  hipMemsetAsync(h0p0, 0, (size_t)64 * 1024 * 2, stream);
  hipMemsetAsync(h0p1, 0, (size_t)64 * 1024 * 2, stream);
  hipMemsetAsync(h1p0, 0, (size_t)64 * 1024 * 2, stream);
  hipMemsetAsync(h1p1, 0, (size_t)64 * 1024 * 2, stream);
  hipMemsetAsync(ctr, 0, 1024, stream);

  hipFuncSetAttribute((const void*)lstm_persist,
                      hipFuncAttributeMaxDynamicSharedMemorySize, LDS_BYTES);
  lstm_persist<<<NBLK, NTHR, LDS_BYTES, stream>>>(
      xf16, We0, We1, Wd0, Wd1,
      ebih0, ebhh0, ebih1, ebhh1, dbih0, dbhh0, dbih1, dbhh1,
      h0p0, h0p1, h1p0, h1p1, femb, out, ctr);
}

// Round 5
// 9188.608 us; speedup vs baseline: 4.6179x; 1.0572x over previous
//
#include <hip/hip_runtime.h>
#include <hip/hip_fp16.h>

// LSTM autoencoder B=64,S=256,D=H=1024,L=2 — persistent kernel, round 5.
// vs round 4: h-state goes to a FRESH 128KB slot per phase (fresh=1 mode).
//   - producers: write-through sc0 sc1 stores (globally visible, no-allocate)
//   - consumers: PLAIN loads (fresh addresses can't be stale in any L2) ->
//     per-XCD L2 absorbs the 96MB/phase broadcast instead of the fabric.
// Falls back to round-4 ping-pong + coherent reads (fresh=0) if ws too small.

#define NBLK 256
#define NTHR 512
#define LDS_BYTES (128 * 1024)
#define HS 65536  // halfs per h slot (64*1024)

typedef _Float16 half8 __attribute__((ext_vector_type(8)));
typedef float    f32x4 __attribute__((ext_vector_type(4)));

__device__ __forceinline__ float sigm_(float x) { return 1.f / (1.f + __expf(-x)); }
__device__ __forceinline__ float tanh_(float x) {
  float e = __expf(-2.f * fabsf(x));
  float r = (1.f - e) / (1.f + e);
  return x >= 0.f ? r : -r;
}

__global__ __launch_bounds__(256) void cvt_x(const float* __restrict__ src,
                                             __half* __restrict__ dst, int n) {
  int i = blockIdx.x * 256 + threadIdx.x;
  if (i < n) dst[i] = __float2half(src[i]);
}

__global__ __launch_bounds__(256) void cvt_wcat(const float* __restrict__ wa,
                                                const float* __restrict__ wb,
                                                __half* __restrict__ dst, int flipA) {
  int i = blockIdx.x * 256 + threadIdx.x;  // over 4096*2048
  if (i >= 4096 * 2048) return;
  int n = i >> 11, k = i & 2047;
  float v = (k < 1024) ? wa[n * 1024 + (flipA ? (1023 - k) : k)]
                       : wb[n * 1024 + (k - 1024)];
  dst[i] = __float2half(v);
}

__global__ void fail_mark(float* out) { out[0] = 1.0e9f; }

// ---- async 8x16B load issue; outputs EARLY-CLOBBER so none alias the addr pair ----
__device__ __forceinline__ void issue8c(const __half* p,
    half8& r0, half8& r1, half8& r2, half8& r3,
    half8& r4, half8& r5, half8& r6, half8& r7) {
  asm volatile(
    "global_load_dwordx4 %0, %8, off sc0 sc1\n\t"
    "global_load_dwordx4 %1, %8, off offset:64 sc0 sc1\n\t"
    "global_load_dwordx4 %2, %8, off offset:128 sc0 sc1\n\t"
    "global_load_dwordx4 %3, %8, off offset:192 sc0 sc1\n\t"
    "global_load_dwordx4 %4, %8, off offset:256 sc0 sc1\n\t"
    "global_load_dwordx4 %5, %8, off offset:320 sc0 sc1\n\t"
    "global_load_dwordx4 %6, %8, off offset:384 sc0 sc1\n\t"
    "global_load_dwordx4 %7, %8, off offset:448 sc0 sc1"
    : "=&v"(r0), "=&v"(r1), "=&v"(r2), "=&v"(r3),
      "=&v"(r4), "=&v"(r5), "=&v"(r6), "=&v"(r7)
    : "v"(p) : "memory");
}
__device__ __forceinline__ void issue8p(const __half* p,
    half8& r0, half8& r1, half8& r2, half8& r3,
    half8& r4, half8& r5, half8& r6, half8& r7) {
  asm volatile(
    "global_load_dwordx4 %0, %8, off\n\t"
    "global_load_dwordx4 %1, %8, off offset:64\n\t"
    "global_load_dwordx4 %2, %8, off offset:128\n\t"
    "global_load_dwordx4 %3, %8, off offset:192\n\t"
    "global_load_dwordx4 %4, %8, off offset:256\n\t"
    "global_load_dwordx4 %5, %8, off offset:320\n\t"
    "global_load_dwordx4 %6, %8, off offset:384\n\t"
    "global_load_dwordx4 %7, %8, off offset:448"
    : "=&v"(r0), "=&v"(r1), "=&v"(r2), "=&v"(r3),
      "=&v"(r4), "=&v"(r5), "=&v"(r6), "=&v"(r7)
    : "v"(p) : "memory");
}

__device__ __forceinline__ void st2_coh(__half* p, float h) {
  unsigned v = (unsigned)__half_as_ushort(__float2half(h));
  asm volatile("global_store_short %0, %1, off sc0 sc1" :: "v"(p), "v"(v) : "memory");
}

__device__ __forceinline__ unsigned poll8(const unsigned* c) {
  unsigned a0, a1, a2, a3, a4, a5, a6, a7;
  asm volatile(
    "global_load_dword %0, %8, off sc0 sc1\n\t"
    "global_load_dword %1, %8, off offset:64 sc0 sc1\n\t"
    "global_load_dword %2, %8, off offset:128 sc0 sc1\n\t"
    "global_load_dword %3, %8, off offset:192 sc0 sc1\n\t"
    "global_load_dword %4, %8, off offset:256 sc0 sc1\n\t"
    "global_load_dword %5, %8, off offset:320 sc0 sc1\n\t"
    "global_load_dword %6, %8, off offset:384 sc0 sc1\n\t"
    "global_load_dword %7, %8, off offset:448 sc0 sc1\n\t"
    "s_waitcnt vmcnt(0)"
    : "=&v"(a0), "=&v"(a1), "=&v"(a2), "=&v"(a3),
      "=&v"(a4), "=&v"(a5), "=&v"(a6), "=&v"(a7)
    : "v"(c) : "memory");
  return a0 + a1 + a2 + a3 + a4 + a5 + a6 + a7;
}

#define WAITVM(n) do { asm volatile("s_waitcnt vmcnt(" #n ")" ::: "memory"); \
                       __builtin_amdgcn_sched_barrier(0); } while (0)
#define BANK(X) X##0, X##1, X##2, X##3, X##4, X##5, X##6, X##7
#define ISSUE(X, c) do { const __half* _p = ((c) < 4 ? pa + (c) * 256 : pb + ((c) - 4) * 256); \
                         if (((c) < 4) ? coh0f : coh1f) issue8c(_p, BANK(X)); \
                         else issue8p(_p, BANK(X)); } while (0)
#define MFMA8(X, c) do { const __half* _b = ldsb + (c) * 8192; \
  acc = __builtin_amdgcn_mfma_f32_16x16x32_f16(X##0, *(const half8*)(_b + 0 * 1024), acc, 0, 0, 0); \
  acc = __builtin_amdgcn_mfma_f32_16x16x32_f16(X##1, *(const half8*)(_b + 1 * 1024), acc, 0, 0, 0); \
  acc = __builtin_amdgcn_mfma_f32_16x16x32_f16(X##2, *(const half8*)(_b + 2 * 1024), acc, 0, 0, 0); \
  acc = __builtin_amdgcn_mfma_f32_16x16x32_f16(X##3, *(const half8*)(_b + 3 * 1024), acc, 0, 0, 0); \
  acc = __builtin_amdgcn_mfma_f32_16x16x32_f16(X##4, *(const half8*)(_b + 4 * 1024), acc, 0, 0, 0); \
  acc = __builtin_amdgcn_mfma_f32_16x16x32_f16(X##5, *(const half8*)(_b + 5 * 1024), acc, 0, 0, 0); \
  acc = __builtin_amdgcn_mfma_f32_16x16x32_f16(X##6, *(const half8*)(_b + 6 * 1024), acc, 0, 0, 0); \
  acc = __builtin_amdgcn_mfma_f32_16x16x32_f16(X##7, *(const half8*)(_b + 7 * 1024), acc, 0, 0, 0); } while (0)

__global__ __launch_bounds__(512) void lstm_persist(
    const __half* __restrict__ xf16,
    const __half* __restrict__ We0, const __half* __restrict__ We1,
    const __half* __restrict__ Wd0, const __half* __restrict__ Wd1,
    const float* __restrict__ ebi0, const float* __restrict__ ebh0,
    const float* __restrict__ ebi1, const float* __restrict__ ebh1,
    const float* __restrict__ dbi0, const float* __restrict__ dbh0,
    const float* __restrict__ dbi1, const float* __restrict__ dbh1,
    __half* hE0, __half* hE1, __half* hD0, __half* hD1,   // no __restrict__: may alias in fallback
    __half* femb, float* __restrict__ out,
    unsigned* __restrict__ ctr, int fresh) {
  extern __shared__ __half lds[];
  const int tid   = threadIdx.x, lane = tid & 63, w = tid >> 6;
  const int layer = blockIdx.x >> 7;
  const int jb    = blockIdx.x & 127;
  const int mtile = w >> 1, nt = w & 1;
  const int c4 = lane & 15, kq = lane >> 4;
  const int gi = c4 >> 2;
  const int arow = mtile * 16 + c4;
  const int ldscol = nt * 16 + c4;
  unsigned* myctr = ctr + (blockIdx.x & 7) * 16;  // 64B apart

  f32x4 c = {0.f, 0.f, 0.f, 0.f};
  unsigned tgt = 0;
  const int cohf = fresh ? 0 : 1;   // h reads: plain in fresh mode, coherent in fallback

  for (int seg = 0; seg < 2; ++seg) {
    const __half* W = (seg == 0) ? (layer ? We1 : We0) : (layer ? Wd1 : Wd0);
    #pragma unroll
    for (int i = 0; i < 16; ++i) {
      int flat = i * 512 + tid;
      int cc = flat >> 8, kk = flat & 255;
      int cc4 = cc & 15, ct = cc >> 4;
      int n = (cc4 >> 2) * 1024 + jb * 8 + ct * 4 + (cc4 & 3);
      *(half8*)(lds + ((size_t)kk * 32 + cc) * 8) =
          *(const half8*)(W + (size_t)n * 2048 + (size_t)kk * 8);
    }
    const float* bi = (seg == 0) ? (layer ? ebi1 : ebi0) : (layer ? dbi1 : dbi0);
    const float* bh = (seg == 0) ? (layer ? ebh1 : ebh0) : (layer ? dbh1 : dbh0);
    const int nlane = gi * 1024 + jb * 8 + nt * 4 + (lane & 3);
    const float bb = bi[nlane] + bh[nlane];
    __syncthreads();
    asm volatile("s_waitcnt vmcnt(0)" ::: "memory");  // clean vmcnt before counted phases

    const __half* ldsb = lds + ((size_t)kq * 32 + ldscol) * 8;
    __half* h0b = seg ? hD0 : hE0;
    __half* h1b = seg ? hD1 : hE1;

    for (int p = 0; p <= 256; ++p) {
      // slot selection (all wave-uniform scalar; fresh: linear, fallback: ping-pong)
      const __half* l0rec = fresh ? ((seg && p == 0) ? hE0 + (size_t)256 * HS
                                                     : h0b + (size_t)p * HS)
                                  : h0b + (size_t)(p & 1) * HS;
      __half* l0wr  = h0b + (size_t)(fresh ? (p + 1) : ((p + 1) & 1)) * HS;
      const __half* l1in = h0b + (size_t)(fresh ? p : (p & 1)) * HS;
      const __half* l1rec = fresh ? ((seg && p == 1) ? hE1 + (size_t)256 * HS
                                                     : h1b + (size_t)(p - 1) * HS)
                                  : h1b + (size_t)((p + 1) & 1) * HS;
      __half* l1wr  = h1b + (size_t)(fresh ? p : (p & 1)) * HS;

      const int active = (layer == 0) ? (p <= 255) : (p >= 1);
      if (active) {
        const __half* s1 = (layer == 0) ? l0rec : l1rec;
        const int coh1f = cohf;
        const __half* s0;
        long long st0;
        int coh0f;
        if (layer == 0) {
          if (seg == 0)      { s0 = xf16 + (size_t)p * 1024;       st0 = 262144; coh0f = 0; }
          else if (p == 0)   { s0 = femb;                          st0 = 1024;   coh0f = 0; }
          else               { s0 = xf16 + (size_t)(p - 1) * 1024; st0 = 262144; coh0f = 0; }
        } else             { s0 = l1in;                            st0 = 1024;   coh0f = cohf; }

        const __half* pa = s0 + (long long)arow * st0 + kq * 8;
        const __half* pb = s1 + (long long)arow * 1024 + kq * 8;
        f32x4 acc = {0.f, 0.f, 0.f, 0.f};
        half8 A0,A1,A2,A3,A4,A5,A6,A7, B0,B1,B2,B3,B4,B5,B6,B7, C0,C1,C2,C3,C4,C5,C6,C7;

        // 8 chunks (0-3: s0, 4-7: s1), 3 banks in flight, counted vmcnt
        ISSUE(A, 0); ISSUE(B, 1); ISSUE(C, 2);
        WAITVM(16); MFMA8(A, 0); ISSUE(A, 3);
        WAITVM(16); MFMA8(B, 1); ISSUE(B, 4);
        WAITVM(16); MFMA8(C, 2); ISSUE(C, 5);
        WAITVM(16); MFMA8(A, 3); ISSUE(A, 6);
        WAITVM(16); MFMA8(B, 4); ISSUE(B, 7);
        WAITVM(16); MFMA8(C, 5);
        WAITVM(8);  MFMA8(A, 6);
        WAITVM(0);  MFMA8(B, 7);

        __half* hdst = (layer == 0) ? l0wr : l1wr;
        const int j = jb * 8 + nt * 4 + (lane & 3);
        #pragma unroll
        for (int r = 0; r < 4; ++r) {
          float v = acc[r] + bb;
          float vx4  = __shfl_xor(v, 4);
          float vx8  = __shfl_xor(v, 8);
          float vx12 = __shfl_xor(vx4, 8);
          float vi = gi == 0 ? v    : gi == 1 ? vx4  : gi == 2 ? vx8  : vx12;
          float vf = gi == 0 ? vx4  : gi == 1 ? v    : gi == 2 ? vx12 : vx8;
          float vg = gi == 0 ? vx8  : gi == 1 ? vx12 : gi == 2 ? v    : vx4;
          float vo = gi == 0 ? vx12 : gi == 1 ? vx8  : gi == 2 ? vx4  : v;
          float cn = sigm_(vf) * c[r] + sigm_(vi) * tanh_(vg);
          c[r] = cn;
          float h = sigm_(vo) * tanh_(cn);
          if (gi == 0) {
            const int b = mtile * 16 + kq * 4 + r;  // C/D row (m89 layout)
            st2_coh(hdst + (size_t)b * 1024 + j, h);
            if (layer == 1) {
              if (seg == 0) {
                if (p == 256) {
                  out[(size_t)b * 1024 + j] = h;                 // emb (plain)
                  st2_coh(femb + (size_t)b * 1024 + (1023 - j), h);
                }
              } else {
                out[65536 + ((size_t)b * 256 + (p - 1)) * 1024 + (1023 - j)] = h;
              }
            }
          }
        }
      }

      // ---- grid barrier: drain coherent stores, arrive on spread counters, poll ----
      tgt += NBLK;
      asm volatile("s_waitcnt vmcnt(0)" ::: "memory");
      __syncthreads();
      if (tid == 0) {
        __hip_atomic_fetch_add(myctr, 1u, __ATOMIC_RELAXED, __HIP_MEMORY_SCOPE_AGENT);
        int guard = 0;
        while (poll8(ctr) < tgt) {
          __builtin_amdgcn_s_sleep(1);
          if (++guard > (1 << 18)) break;  // hang safety: break (wrong results, no hang)
        }
      }
      __syncthreads();
    }
  }
}

extern "C" void kernel_launch(void* const* d_in, const int* in_sizes, int n_in,
                              void* d_out, int out_size, void* d_ws, size_t ws_size,
                              hipStream_t stream) {
  const float* x     = (const float*)d_in[0];
  const float* eWih0 = (const float*)d_in[1];
  const float* eWhh0 = (const float*)d_in[2];
  const float* ebih0 = (const float*)d_in[3];
  const float* ebhh0 = (const float*)d_in[4];
  const float* eWih1 = (const float*)d_in[5];
  const float* eWhh1 = (const float*)d_in[6];
  const float* ebih1 = (const float*)d_in[7];
  const float* ebhh1 = (const float*)d_in[8];
  const float* dWih0 = (const float*)d_in[9];
  const float* dWhh0 = (const float*)d_in[10];
  const float* dbih0 = (const float*)d_in[11];
  const float* dbhh0 = (const float*)d_in[12];
  const float* dWih1 = (const float*)d_in[13];
  const float* dWhh1 = (const float*)d_in[14];
  const float* dbih1 = (const float*)d_in[15];
  const float* dbhh1 = (const float*)d_in[16];
  float* out = (float*)d_out;

  char* ws = (char*)d_ws;
  size_t off = 0;
  auto alloc = [&](size_t bytes) { char* p = ws + off; off += (bytes + 255) & ~(size_t)255; return p; };
  const size_t WCB  = (size_t)4096 * 2048 * sizeof(__half);   // 16MB
  const size_t SLOT = (size_t)HS * sizeof(__half);            // 128KB
  __half* xf16 = (__half*)alloc((size_t)64 * 256 * 1024 * sizeof(__half));  // 32MB
  __half* We0  = (__half*)alloc(WCB);
  __half* We1  = (__half*)alloc(WCB);
  __half* Wd0  = (__half*)alloc(WCB);
  __half* Wd1  = (__half*)alloc(WCB);
  size_t fixed_end = off;

  // try fresh layout (4 sequences x 257 slots)
  int fresh = 1;
  __half *hE0, *hE1, *hD0, *hD1, *femb;
  unsigned* ctr;
  hE0 = (__half*)alloc(257 * SLOT);
  hE1 = (__half*)alloc(257 * SLOT);
  hD0 = (__half*)alloc(257 * SLOT);
  hD1 = (__half*)alloc(257 * SLOT);
  femb = (__half*)alloc(SLOT);
  ctr  = (unsigned*)alloc(1024);
  if (ws_size < off) {
    // fallback: round-4 ping-pong (2 slots per sequence, coherent reads)
    fresh = 0;
    off = fixed_end;
    hE0 = (__half*)alloc(2 * SLOT);
    hE1 = (__half*)alloc(2 * SLOT);
    hD0 = hE0;
    hD1 = hE1;
    femb = (__half*)alloc(SLOT);
    ctr  = (unsigned*)alloc(1024);
    if (ws_size < off) {
      hipLaunchKernelGGL(fail_mark, dim3(1), dim3(1), 0, stream, out);
      return;
    }
  }

  const int xn = 64 * 256 * 1024;
  cvt_x<<<(xn + 255) / 256, 256, 0, stream>>>(x, xf16, xn);
  const int wg = (4096 * 2048 + 255) / 256;
  cvt_wcat<<<wg, 256, 0, stream>>>(eWih0, eWhh0, We0, 0);
  cvt_wcat<<<wg, 256, 0, stream>>>(eWih1, eWhh1, We1, 0);
  cvt_wcat<<<wg, 256, 0, stream>>>(dWih0, dWhh0, Wd0, 1);  // flipped input-cols
  cvt_wcat<<<wg, 256, 0, stream>>>(dWih1, dWhh1, Wd1, 0);

  hipMemsetAsync(hE0, 0, SLOT, stream);  // h0(0) = 0
  hipMemsetAsync(hE1, 0, SLOT, stream);  // h1(0) = 0
  hipMemsetAsync(ctr, 0, 1024, stream);

  hipFuncSetAttribute((const void*)lstm_persist,
                      hipFuncAttributeMaxDynamicSharedMemorySize, LDS_BYTES);
  lstm_persist<<<NBLK, NTHR, LDS_BYTES, stream>>>(
      xf16, We0, We1, Wd0, Wd1,
      ebih0, ebhh0, ebih1, ebhh1, dbih0, dbhh0, dbih1, dbhh1,
      hE0, hE1, hD0, hD1, femb, out, ctr, fresh);
}

// Round 6
// 6961.083 us; speedup vs baseline: 6.0956x; 1.3200x over previous
//
#include <hip/hip_runtime.h>
#include <hip/hip_fp16.h>

// LSTM autoencoder B=64,S=256,D=H=1024,L=2 — persistent kernel, round 6.
// vs round 5:
//  * ws cut 228MB -> ~164MB so FRESH mode can actually run (r5 counters proved
//    the fallback ran: WRITE_SIZE bit-identical to r4). Weight f16 copies gone —
//    LDS weights staged directly from the f32 inputs per segment (flip folded in).
//  * 4 waves/block (one m-tile each, both n-halves) -> A-load volume halved.
//    Latency hidden by a 4-bank x 8-chunk counted-vmcnt pipeline (1 wave/SIMD).
// Coherence: producers write h with sc0 sc1 (visible at IF); fresh mode reads h
// PLAIN from never-before-touched slot addresses (L2-absorbed broadcast);
// fallback mode (ws too small) reads h coherently from ping-pong slots.

#define NBLK 256
#define NTHR 256
#define LDS_BYTES (128 * 1024)
#define HS 65536  // halfs per h slot (64*1024)

typedef _Float16 half8 __attribute__((ext_vector_type(8)));
typedef float    f32x4 __attribute__((ext_vector_type(4)));

__device__ __forceinline__ float sigm_(float x) { return 1.f / (1.f + __expf(-x)); }
__device__ __forceinline__ float tanh_(float x) {
  float e = __expf(-2.f * fabsf(x));
  float r = (1.f - e) / (1.f + e);
  return x >= 0.f ? r : -r;
}

__global__ __launch_bounds__(256) void cvt_x(const float* __restrict__ src,
                                             __half* __restrict__ dst, int n) {
  int i = blockIdx.x * 256 + threadIdx.x;
  if (i < n) dst[i] = __float2half(src[i]);
}

__global__ void fail_mark(float* out) { out[0] = 1.0e9f; }

// ---- async 8x16B load issue; outputs EARLY-CLOBBER so none alias the addr pair ----
__device__ __forceinline__ void issue8c(const __half* p,
    half8& r0, half8& r1, half8& r2, half8& r3,
    half8& r4, half8& r5, half8& r6, half8& r7) {
  asm volatile(
    "global_load_dwordx4 %0, %8, off sc0 sc1\n\t"
    "global_load_dwordx4 %1, %8, off offset:64 sc0 sc1\n\t"
    "global_load_dwordx4 %2, %8, off offset:128 sc0 sc1\n\t"
    "global_load_dwordx4 %3, %8, off offset:192 sc0 sc1\n\t"
    "global_load_dwordx4 %4, %8, off offset:256 sc0 sc1\n\t"
    "global_load_dwordx4 %5, %8, off offset:320 sc0 sc1\n\t"
    "global_load_dwordx4 %6, %8, off offset:384 sc0 sc1\n\t"
    "global_load_dwordx4 %7, %8, off offset:448 sc0 sc1"
    : "=&v"(r0), "=&v"(r1), "=&v"(r2), "=&v"(r3),
      "=&v"(r4), "=&v"(r5), "=&v"(r6), "=&v"(r7)
    : "v"(p) : "memory");
}
__device__ __forceinline__ void issue8p(const __half* p,
    half8& r0, half8& r1, half8& r2, half8& r3,
    half8& r4, half8& r5, half8& r6, half8& r7) {
  asm volatile(
    "global_load_dwordx4 %0, %8, off\n\t"
    "global_load_dwordx4 %1, %8, off offset:64\n\t"
    "global_load_dwordx4 %2, %8, off offset:128\n\t"
    "global_load_dwordx4 %3, %8, off offset:192\n\t"
    "global_load_dwordx4 %4, %8, off offset:256\n\t"
    "global_load_dwordx4 %5, %8, off offset:320\n\t"
    "global_load_dwordx4 %6, %8, off offset:384\n\t"
    "global_load_dwordx4 %7, %8, off offset:448"
    : "=&v"(r0), "=&v"(r1), "=&v"(r2), "=&v"(r3),
      "=&v"(r4), "=&v"(r5), "=&v"(r6), "=&v"(r7)
    : "v"(p) : "memory");
}

__device__ __forceinline__ void st2_coh(__half* p, float h) {
  unsigned v = (unsigned)__half_as_ushort(__float2half(h));
  asm volatile("global_store_short %0, %1, off sc0 sc1" :: "v"(p), "v"(v) : "memory");
}

__device__ __forceinline__ unsigned poll8(const unsigned* c) {
  unsigned a0, a1, a2, a3, a4, a5, a6, a7;
  asm volatile(
    "global_load_dword %0, %8, off sc0 sc1\n\t"
    "global_load_dword %1, %8, off offset:64 sc0 sc1\n\t"
    "global_load_dword %2, %8, off offset:128 sc0 sc1\n\t"
    "global_load_dword %3, %8, off offset:192 sc0 sc1\n\t"
    "global_load_dword %4, %8, off offset:256 sc0 sc1\n\t"
    "global_load_dword %5, %8, off offset:320 sc0 sc1\n\t"
    "global_load_dword %6, %8, off offset:384 sc0 sc1\n\t"
    "global_load_dword %7, %8, off offset:448 sc0 sc1\n\t"
    "s_waitcnt vmcnt(0)"
    : "=&v"(a0), "=&v"(a1), "=&v"(a2), "=&v"(a3),
      "=&v"(a4), "=&v"(a5), "=&v"(a6), "=&v"(a7)
    : "v"(c) : "memory");
  return a0 + a1 + a2 + a3 + a4 + a5 + a6 + a7;
}

#define WAITVM(n) do { asm volatile("s_waitcnt vmcnt(" #n ")" ::: "memory"); \
                       __builtin_amdgcn_sched_barrier(0); } while (0)
#define BANK(X) X##0, X##1, X##2, X##3, X##4, X##5, X##6, X##7
#define ISSUE(X, c) do { const __half* _p = ((c) < 4 ? pa + (c) * 256 : pb + ((c) - 4) * 256); \
                         if (((c) < 4) ? coh0f : coh1f) issue8c(_p, BANK(X)); \
                         else issue8p(_p, BANK(X)); } while (0)
// 16 MFMAs per chunk: two independent acc chains (n=0 cols 0-15, n=1 cols 16-31) interleaved
#define MFMA16(X, c) do { const __half* _b = ldsb + (c) * 8192; \
  accA = __builtin_amdgcn_mfma_f32_16x16x32_f16(X##0, *(const half8*)(_b + 0*1024), accA, 0,0,0); \
  accB = __builtin_amdgcn_mfma_f32_16x16x32_f16(X##0, *(const half8*)(_b + 0*1024 + 128), accB, 0,0,0); \
  accA = __builtin_amdgcn_mfma_f32_16x16x32_f16(X##1, *(const half8*)(_b + 1*1024), accA, 0,0,0); \
  accB = __builtin_amdgcn_mfma_f32_16x16x32_f16(X##1, *(const half8*)(_b + 1*1024 + 128), accB, 0,0,0); \
  accA = __builtin_amdgcn_mfma_f32_16x16x32_f16(X##2, *(const half8*)(_b + 2*1024), accA, 0,0,0); \
  accB = __builtin_amdgcn_mfma_f32_16x16x32_f16(X##2, *(const half8*)(_b + 2*1024 + 128), accB, 0,0,0); \
  accA = __builtin_amdgcn_mfma_f32_16x16x32_f16(X##3, *(const half8*)(_b + 3*1024), accA, 0,0,0); \
  accB = __builtin_amdgcn_mfma_f32_16x16x32_f16(X##3, *(const half8*)(_b + 3*1024 + 128), accB, 0,0,0); \
  accA = __builtin_amdgcn_mfma_f32_16x16x32_f16(X##4, *(const half8*)(_b + 4*1024), accA, 0,0,0); \
  accB = __builtin_amdgcn_mfma_f32_16x16x32_f16(X##4, *(const half8*)(_b + 4*1024 + 128), accB, 0,0,0); \
  accA = __builtin_amdgcn_mfma_f32_16x16x32_f16(X##5, *(const half8*)(_b + 5*1024), accA, 0,0,0); \
  accB = __builtin_amdgcn_mfma_f32_16x16x32_f16(X##5, *(const half8*)(_b + 5*1024 + 128), accB, 0,0,0); \
  accA = __builtin_amdgcn_mfma_f32_16x16x32_f16(X##6, *(const half8*)(_b + 6*1024), accA, 0,0,0); \
  accB = __builtin_amdgcn_mfma_f32_16x16x32_f16(X##6, *(const half8*)(_b + 6*1024 + 128), accB, 0,0,0); \
  accA = __builtin_amdgcn_mfma_f32_16x16x32_f16(X##7, *(const half8*)(_b + 7*1024), accA, 0,0,0); \
  accB = __builtin_amdgcn_mfma_f32_16x16x32_f16(X##7, *(const half8*)(_b + 7*1024 + 128), accB, 0,0,0); \
  } while (0)

// LSTM cell epilogue for one n-tile (gate allgather via xor-4/8 within the 16-col group)
#define EPI(ACC, CST, BB, NIDX) do { \
  _Pragma("unroll") \
  for (int r = 0; r < 4; ++r) { \
    float v = ACC[r] + (BB); \
    float vx4  = __shfl_xor(v, 4); \
    float vx8  = __shfl_xor(v, 8); \
    float vx12 = __shfl_xor(vx4, 8); \
    float vi = gi == 0 ? v    : gi == 1 ? vx4  : gi == 2 ? vx8  : vx12; \
    float vf = gi == 0 ? vx4  : gi == 1 ? v    : gi == 2 ? vx12 : vx8; \
    float vg = gi == 0 ? vx8  : gi == 1 ? vx12 : gi == 2 ? v    : vx4; \
    float vo = gi == 0 ? vx12 : gi == 1 ? vx8  : gi == 2 ? vx4  : v; \
    float cn = sigm_(vf) * CST[r] + sigm_(vi) * tanh_(vg); \
    CST[r] = cn; \
    float h = sigm_(vo) * tanh_(cn); \
    if (gi == 0) { \
      const int b = mtile * 16 + kq * 4 + r; \
      const int j = jb * 8 + (NIDX) * 4 + (lane & 3); \
      st2_coh(hdst + (size_t)b * 1024 + j, h); \
      if (layer == 1) { \
        if (seg == 0) { if (p == 256) { \
            out[(size_t)b * 1024 + j] = h; \
            st2_coh(femb + (size_t)b * 1024 + (1023 - j), h); } \
        } else { \
          out[65536 + ((size_t)b * 256 + (p - 1)) * 1024 + (1023 - j)] = h; } \
      } \
    } \
  } } while (0)

__global__ __launch_bounds__(256, 1) void lstm_persist(
    const __half* __restrict__ xf16,
    const float* __restrict__ eWih0, const float* __restrict__ eWhh0,
    const float* __restrict__ eWih1, const float* __restrict__ eWhh1,
    const float* __restrict__ dWih0, const float* __restrict__ dWhh0,
    const float* __restrict__ dWih1, const float* __restrict__ dWhh1,
    const float* __restrict__ ebi0, const float* __restrict__ ebh0,
    const float* __restrict__ ebi1, const float* __restrict__ ebh1,
    const float* __restrict__ dbi0, const float* __restrict__ dbh0,
    const float* __restrict__ dbi1, const float* __restrict__ dbh1,
    __half* hE0, __half* hE1, __half* hD0, __half* hD1,   // may alias in fallback
    __half* femb, float* __restrict__ out,
    unsigned* __restrict__ ctr, int fresh) {
  extern __shared__ __half lds[];
  const int tid   = threadIdx.x, lane = tid & 63;
  const int mtile = tid >> 6;          // wave id = m-tile (batch rows mtile*16..+16)
  const int layer = blockIdx.x >> 7;
  const int jb    = blockIdx.x & 127;
  const int c4 = lane & 15, kq = lane >> 4;
  const int gi = c4 >> 2;
  const int arow = mtile * 16 + c4;
  unsigned* myctr = ctr + (blockIdx.x & 7) * 16;  // 64B apart

  f32x4 cA = {0.f, 0.f, 0.f, 0.f};     // cell state (n=0 tile), regs across enc->dec
  f32x4 cB = {0.f, 0.f, 0.f, 0.f};     // cell state (n=1 tile)
  unsigned tgt = 0;
  const int cohf = fresh ? 0 : 1;

  for (int seg = 0; seg < 2; ++seg) {
    // ---- stage [32 cols x 2048 K] f16 weights into LDS from the f32 inputs ----
    const float* Wih; const float* Whh; int flip = 0;
    if (seg == 0) { Wih = layer ? eWih1 : eWih0; Whh = layer ? eWhh1 : eWhh0; }
    else { Wih = layer ? dWih1 : dWih0; Whh = layer ? dWhh1 : dWhh0; flip = (layer == 0); }
    const int k0 = tid * 8;
    for (int i = 0; i < 32; ++i) {      // i = LDS column, thread covers K-chunk tid
      int cc4 = i & 15, ct = i >> 4;
      int n = (cc4 >> 2) * 1024 + jb * 8 + ct * 4 + (cc4 & 3);
      half8 t;
      if (k0 < 1024) {
        if (flip) {
          #pragma unroll
          for (int e = 0; e < 8; ++e) t[e] = (_Float16)Wih[(size_t)n * 1024 + 1023 - k0 - e];
        } else {
          #pragma unroll
          for (int e = 0; e < 8; ++e) t[e] = (_Float16)Wih[(size_t)n * 1024 + k0 + e];
        }
      } else {
        #pragma unroll
        for (int e = 0; e < 8; ++e) t[e] = (_Float16)Whh[(size_t)n * 1024 + k0 - 1024 + e];
      }
      *(half8*)(lds + ((size_t)tid * 32 + i) * 8) = t;
    }
    const float* bi = (seg == 0) ? (layer ? ebi1 : ebi0) : (layer ? dbi1 : dbi0);
    const float* bh = (seg == 0) ? (layer ? ebh1 : ebh0) : (layer ? dbh1 : dbh0);
    const int nl0 = gi * 1024 + jb * 8 + (lane & 3);
    const float bb0 = bi[nl0] + bh[nl0];
    const float bb1 = bi[nl0 + 4] + bh[nl0 + 4];
    __syncthreads();
    asm volatile("s_waitcnt vmcnt(0)" ::: "memory");  // clean vmcnt before counted phases

    const __half* ldsb = lds + ((size_t)kq * 32 + c4) * 8;
    __half* h0b = seg ? hD0 : hE0;
    __half* h1b = seg ? hD1 : hE1;

    for (int p = 0; p <= 256; ++p) {
      // slot selection (wave-uniform; fresh: linear fresh slots, fallback: ping-pong)
      const __half* l0rec = fresh ? ((seg && p == 0) ? hE0 + (size_t)256 * HS
                                                     : h0b + (size_t)p * HS)
                                  : h0b + (size_t)(p & 1) * HS;
      __half* l0wr  = h0b + (size_t)(fresh ? (p + 1) : ((p + 1) & 1)) * HS;
      const __half* l1in = h0b + (size_t)(fresh ? p : (p & 1)) * HS;
      const __half* l1rec = fresh ? ((seg && p == 1) ? hE1 + (size_t)256 * HS
                                                     : h1b + (size_t)(p - 1) * HS)
                                  : h1b + (size_t)((p + 1) & 1) * HS;
      __half* l1wr  = h1b + (size_t)(fresh ? p : (p & 1)) * HS;

      const int active = (layer == 0) ? (p <= 255) : (p >= 1);
      if (active) {
        const __half* s1 = (layer == 0) ? l0rec : l1rec;
        const int coh1f = cohf;
        const __half* s0;
        long long st0;
        int coh0f;
        if (layer == 0) {
          if (seg == 0)      { s0 = xf16 + (size_t)p * 1024;       st0 = 262144; coh0f = 0; }
          else if (p == 0)   { s0 = femb;                          st0 = 1024;   coh0f = 0; }
          else               { s0 = xf16 + (size_t)(p - 1) * 1024; st0 = 262144; coh0f = 0; }
        } else             { s0 = l1in;                            st0 = 1024;   coh0f = cohf; }

        const __half* pa = s0 + (long long)arow * st0 + kq * 8;
        const __half* pb = s1 + (long long)arow * 1024 + kq * 8;
        f32x4 accA = {0.f, 0.f, 0.f, 0.f};
        f32x4 accB = {0.f, 0.f, 0.f, 0.f};
        half8 A0,A1,A2,A3,A4,A5,A6,A7, B0,B1,B2,B3,B4,B5,B6,B7,
              C0,C1,C2,C3,C4,C5,C6,C7, D0,D1,D2,D3,D4,D5,D6,D7;

        // 8 chunks (0-3: s0, 4-7: s1), 4 banks in flight, counted vmcnt
        ISSUE(A, 0); ISSUE(B, 1); ISSUE(C, 2); ISSUE(D, 3);
        WAITVM(24); MFMA16(A, 0); ISSUE(A, 4);
        WAITVM(24); MFMA16(B, 1); ISSUE(B, 5);
        WAITVM(24); MFMA16(C, 2); ISSUE(C, 6);
        WAITVM(24); MFMA16(D, 3); ISSUE(D, 7);
        WAITVM(24); MFMA16(A, 4);
        WAITVM(16); MFMA16(B, 5);
        WAITVM(8);  MFMA16(C, 6);
        WAITVM(0);  MFMA16(D, 7);

        __half* hdst = (layer == 0) ? l0wr : l1wr;
        EPI(accA, cA, bb0, 0);
        EPI(accB, cB, bb1, 1);
      }

      // ---- grid barrier: drain coherent stores, arrive on spread counters, poll ----
      tgt += NBLK;
      asm volatile("s_waitcnt vmcnt(0)" ::: "memory");
      __syncthreads();
      if (tid == 0) {
        __hip_atomic_fetch_add(myctr, 1u, __ATOMIC_RELAXED, __HIP_MEMORY_SCOPE_AGENT);
        int guard = 0;
        while (poll8(ctr) < tgt) {
          __builtin_amdgcn_s_sleep(1);
          if (++guard > (1 << 18)) break;  // hang safety: break (wrong results, no hang)
        }
      }
      __syncthreads();
    }
  }
}

extern "C" void kernel_launch(void* const* d_in, const int* in_sizes, int n_in,
                              void* d_out, int out_size, void* d_ws, size_t ws_size,
                              hipStream_t stream) {
  const float* x     = (const float*)d_in[0];
  const float* eWih0 = (const float*)d_in[1];
  const float* eWhh0 = (const float*)d_in[2];
  const float* ebih0 = (const float*)d_in[3];
  const float* ebhh0 = (const float*)d_in[4];
  const float* eWih1 = (const float*)d_in[5];
  const float* eWhh1 = (const float*)d_in[6];
  const float* ebih1 = (const float*)d_in[7];
  const float* ebhh1 = (const float*)d_in[8];
  const float* dWih0 = (const float*)d_in[9];
  const float* dWhh0 = (const float*)d_in[10];
  const float* dbih0 = (const float*)d_in[11];
  const float* dbhh0 = (const float*)d_in[12];
  const float* dWih1 = (const float*)d_in[13];
  const float* dWhh1 = (const float*)d_in[14];
  const float* dbih1 = (const float*)d_in[15];
  const float* dbhh1 = (const float*)d_in[16];
  float* out = (float*)d_out;

  char* ws = (char*)d_ws;
  size_t off = 0;
  auto alloc = [&](size_t bytes) { char* p = ws + off; off += (bytes + 255) & ~(size_t)255; return p; };
  const size_t SLOT = (size_t)HS * sizeof(__half);            // 128KB
  __half* xf16 = (__half*)alloc((size_t)64 * 256 * 1024 * sizeof(__half));  // 32MB
  size_t fixed_end = off;

  // try fresh layout (4 sequences x 257 slots = 131.5MB; total ~164MB)
  int fresh = 1;
  __half *hE0, *hE1, *hD0, *hD1, *femb;
  unsigned* ctr;
  hE0 = (__half*)alloc(257 * SLOT);
  hE1 = (__half*)alloc(257 * SLOT);
  hD0 = (__half*)alloc(257 * SLOT);
  hD1 = (__half*)alloc(257 * SLOT);
  femb = (__half*)alloc(SLOT);
  ctr  = (unsigned*)alloc(1024);
  if (ws_size < off) {
    // fallback: ping-pong (2 slots per layer) + coherent reads (~33MB total)
    fresh = 0;
    off = fixed_end;
    hE0 = (__half*)alloc(2 * SLOT);
    hE1 = (__half*)alloc(2 * SLOT);
    hD0 = hE0;
    hD1 = hE1;
    femb = (__half*)alloc(SLOT);
    ctr  = (unsigned*)alloc(1024);
    if (ws_size < off) {
      hipLaunchKernelGGL(fail_mark, dim3(1), dim3(1), 0, stream, out);
      return;
    }
  }

  const int xn = 64 * 256 * 1024;
  cvt_x<<<(xn + 255) / 256, 256, 0, stream>>>(x, xf16, xn);

  hipMemsetAsync(hE0, 0, SLOT, stream);  // h0 slot0 = zeros
  hipMemsetAsync(hE1, 0, SLOT, stream);  // h1 slot0 = zeros
  hipMemsetAsync(ctr, 0, 1024, stream);

  hipFuncSetAttribute((const void*)lstm_persist,
                      hipFuncAttributeMaxDynamicSharedMemorySize, LDS_BYTES);
  lstm_persist<<<NBLK, NTHR, LDS_BYTES, stream>>>(
      xf16,
      eWih0, eWhh0, eWih1, eWhh1, dWih0, dWhh0, dWih1, dWhh1,
      ebih0, ebhh0, ebih1, ebhh1, dbih0, dbhh0, dbih1, dbhh1,
      hE0, hE1, hD0, hD1, femb, out, ctr, fresh);
}

// Round 7
// 6953.642 us; speedup vs baseline: 6.1021x; 1.0011x over previous
//
#include <hip/hip_runtime.h>
#include <hip/hip_fp16.h>

// LSTM autoencoder B=64,S=256,D=H=1024,L=2 — persistent kernel, round 7.
// vs round 6: fresh-slot (never-reused-address) h0 state actually FITS:
//   ws = xf16 32MB + 2x257 h0 slots 64.3MB + h1 ping-pong 256KB + femb ~ 96.7MB
//   (r1 proved ws >= ~105MB, so no silent fallback possible; if it still
//    doesn't fit, out[0] = 1e6*ws_MB reports ws_size via the absmax error.)
// Read modes: ALL h0 reads plain (fresh addresses -> per-XCD L2 absorbs the
// broadcast); h1 recurrent reads sc0 sc1 (ping-pong, r4-proven); all h stores
// write-through sc0 sc1 (visible at IC for peer-XCD plain reads).

#define NBLK 256
#define NTHR 256
#define LDS_BYTES (128 * 1024)
#define HS 65536  // halfs per h slot (64*1024)

typedef _Float16 half8 __attribute__((ext_vector_type(8)));
typedef float    f32x4 __attribute__((ext_vector_type(4)));

__device__ __forceinline__ float sigm_(float x) { return 1.f / (1.f + __expf(-x)); }
__device__ __forceinline__ float tanh_(float x) {
  float e = __expf(-2.f * fabsf(x));
  float r = (1.f - e) / (1.f + e);
  return x >= 0.f ? r : -r;
}

__global__ __launch_bounds__(256) void cvt_x(const float* __restrict__ src,
                                             __half* __restrict__ dst, int n) {
  int i = blockIdx.x * 256 + threadIdx.x;
  if (i < n) dst[i] = __float2half(src[i]);
}

__global__ void fail_mark(float* out, float ws_mb) { out[0] = 1.0e6f * ws_mb; }

// ---- async 8x16B load issue; outputs EARLY-CLOBBER so none alias the addr pair ----
__device__ __forceinline__ void issue8c(const __half* p,
    half8& r0, half8& r1, half8& r2, half8& r3,
    half8& r4, half8& r5, half8& r6, half8& r7) {
  asm volatile(
    "global_load_dwordx4 %0, %8, off sc0 sc1\n\t"
    "global_load_dwordx4 %1, %8, off offset:64 sc0 sc1\n\t"
    "global_load_dwordx4 %2, %8, off offset:128 sc0 sc1\n\t"
    "global_load_dwordx4 %3, %8, off offset:192 sc0 sc1\n\t"
    "global_load_dwordx4 %4, %8, off offset:256 sc0 sc1\n\t"
    "global_load_dwordx4 %5, %8, off offset:320 sc0 sc1\n\t"
    "global_load_dwordx4 %6, %8, off offset:384 sc0 sc1\n\t"
    "global_load_dwordx4 %7, %8, off offset:448 sc0 sc1"
    : "=&v"(r0), "=&v"(r1), "=&v"(r2), "=&v"(r3),
      "=&v"(r4), "=&v"(r5), "=&v"(r6), "=&v"(r7)
    : "v"(p) : "memory");
}
__device__ __forceinline__ void issue8p(const __half* p,
    half8& r0, half8& r1, half8& r2, half8& r3,
    half8& r4, half8& r5, half8& r6, half8& r7) {
  asm volatile(
    "global_load_dwordx4 %0, %8, off\n\t"
    "global_load_dwordx4 %1, %8, off offset:64\n\t"
    "global_load_dwordx4 %2, %8, off offset:128\n\t"
    "global_load_dwordx4 %3, %8, off offset:192\n\t"
    "global_load_dwordx4 %4, %8, off offset:256\n\t"
    "global_load_dwordx4 %5, %8, off offset:320\n\t"
    "global_load_dwordx4 %6, %8, off offset:384\n\t"
    "global_load_dwordx4 %7, %8, off offset:448"
    : "=&v"(r0), "=&v"(r1), "=&v"(r2), "=&v"(r3),
      "=&v"(r4), "=&v"(r5), "=&v"(r6), "=&v"(r7)
    : "v"(p) : "memory");
}

__device__ __forceinline__ void st2_coh(__half* p, float h) {
  unsigned v = (unsigned)__half_as_ushort(__float2half(h));
  asm volatile("global_store_short %0, %1, off sc0 sc1" :: "v"(p), "v"(v) : "memory");
}

__device__ __forceinline__ unsigned poll8(const unsigned* c) {
  unsigned a0, a1, a2, a3, a4, a5, a6, a7;
  asm volatile(
    "global_load_dword %0, %8, off sc0 sc1\n\t"
    "global_load_dword %1, %8, off offset:64 sc0 sc1\n\t"
    "global_load_dword %2, %8, off offset:128 sc0 sc1\n\t"
    "global_load_dword %3, %8, off offset:192 sc0 sc1\n\t"
    "global_load_dword %4, %8, off offset:256 sc0 sc1\n\t"
    "global_load_dword %5, %8, off offset:320 sc0 sc1\n\t"
    "global_load_dword %6, %8, off offset:384 sc0 sc1\n\t"
    "global_load_dword %7, %8, off offset:448 sc0 sc1\n\t"
    "s_waitcnt vmcnt(0)"
    : "=&v"(a0), "=&v"(a1), "=&v"(a2), "=&v"(a3),
      "=&v"(a4), "=&v"(a5), "=&v"(a6), "=&v"(a7)
    : "v"(c) : "memory");
  return a0 + a1 + a2 + a3 + a4 + a5 + a6 + a7;
}

#define WAITVM(n) do { asm volatile("s_waitcnt vmcnt(" #n ")" ::: "memory"); \
                       __builtin_amdgcn_sched_barrier(0); } while (0)
#define BANK(X) X##0, X##1, X##2, X##3, X##4, X##5, X##6, X##7
// chunks 0-3: s0 (always plain); chunks 4-7: s1 (coherent only for layer-1 = h1 recurrent)
#define ISSUE(X, c) do { const __half* _p = ((c) < 4 ? pa + (c) * 256 : pb + ((c) - 4) * 256); \
                         if (((c) >= 4) && coh1) issue8c(_p, BANK(X)); \
                         else issue8p(_p, BANK(X)); } while (0)
// 16 MFMAs per chunk: two independent acc chains (n=0 cols 0-15, n=1 cols 16-31) interleaved
#define MFMA16(X, c) do { const __half* _b = ldsb + (c) * 8192; \
  accA = __builtin_amdgcn_mfma_f32_16x16x32_f16(X##0, *(const half8*)(_b + 0*1024), accA, 0,0,0); \
  accB = __builtin_amdgcn_mfma_f32_16x16x32_f16(X##0, *(const half8*)(_b + 0*1024 + 128), accB, 0,0,0); \
  accA = __builtin_amdgcn_mfma_f32_16x16x32_f16(X##1, *(const half8*)(_b + 1*1024), accA, 0,0,0); \
  accB = __builtin_amdgcn_mfma_f32_16x16x32_f16(X##1, *(const half8*)(_b + 1*1024 + 128), accB, 0,0,0); \
  accA = __builtin_amdgcn_mfma_f32_16x16x32_f16(X##2, *(const half8*)(_b + 2*1024), accA, 0,0,0); \
  accB = __builtin_amdgcn_mfma_f32_16x16x32_f16(X##2, *(const half8*)(_b + 2*1024 + 128), accB, 0,0,0); \
  accA = __builtin_amdgcn_mfma_f32_16x16x32_f16(X##3, *(const half8*)(_b + 3*1024), accA, 0,0,0); \
  accB = __builtin_amdgcn_mfma_f32_16x16x32_f16(X##3, *(const half8*)(_b + 3*1024 + 128), accB, 0,0,0); \
  accA = __builtin_amdgcn_mfma_f32_16x16x32_f16(X##4, *(const half8*)(_b + 4*1024), accA, 0,0,0); \
  accB = __builtin_amdgcn_mfma_f32_16x16x32_f16(X##4, *(const half8*)(_b + 4*1024 + 128), accB, 0,0,0); \
  accA = __builtin_amdgcn_mfma_f32_16x16x32_f16(X##5, *(const half8*)(_b + 5*1024), accA, 0,0,0); \
  accB = __builtin_amdgcn_mfma_f32_16x16x32_f16(X##5, *(const half8*)(_b + 5*1024 + 128), accB, 0,0,0); \
  accA = __builtin_amdgcn_mfma_f32_16x16x32_f16(X##6, *(const half8*)(_b + 6*1024), accA, 0,0,0); \
  accB = __builtin_amdgcn_mfma_f32_16x16x32_f16(X##6, *(const half8*)(_b + 6*1024 + 128), accB, 0,0,0); \
  accA = __builtin_amdgcn_mfma_f32_16x16x32_f16(X##7, *(const half8*)(_b + 7*1024), accA, 0,0,0); \
  accB = __builtin_amdgcn_mfma_f32_16x16x32_f16(X##7, *(const half8*)(_b + 7*1024 + 128), accB, 0,0,0); \
  } while (0)

// LSTM cell epilogue for one n-tile (gate allgather via xor-4/8 within the 16-col group)
#define EPI(ACC, CST, BB, NIDX) do { \
  _Pragma("unroll") \
  for (int r = 0; r < 4; ++r) { \
    float v = ACC[r] + (BB); \
    float vx4  = __shfl_xor(v, 4); \
    float vx8  = __shfl_xor(v, 8); \
    float vx12 = __shfl_xor(vx4, 8); \
    float vi = gi == 0 ? v    : gi == 1 ? vx4  : gi == 2 ? vx8  : vx12; \
    float vf = gi == 0 ? vx4  : gi == 1 ? v    : gi == 2 ? vx12 : vx8; \
    float vg = gi == 0 ? vx8  : gi == 1 ? vx12 : gi == 2 ? v    : vx4; \
    float vo = gi == 0 ? vx12 : gi == 1 ? vx8  : gi == 2 ? vx4  : v; \
    float cn = sigm_(vf) * CST[r] + sigm_(vi) * tanh_(vg); \
    CST[r] = cn; \
    float h = sigm_(vo) * tanh_(cn); \
    if (gi == 0) { \
      const int b = mtile * 16 + kq * 4 + r; \
      const int j = jb * 8 + (NIDX) * 4 + (lane & 3); \
      st2_coh(hdst + (size_t)b * 1024 + j, h); \
      if (layer == 1) { \
        if (seg == 0) { if (p == 256) { \
            out[(size_t)b * 1024 + j] = h; \
            st2_coh(femb + (size_t)b * 1024 + (1023 - j), h); } \
        } else { \
          out[65536 + ((size_t)b * 256 + (p - 1)) * 1024 + (1023 - j)] = h; } \
      } \
    } \
  } } while (0)

__global__ __launch_bounds__(256, 1) void lstm_persist(
    const __half* __restrict__ xf16,
    const float* __restrict__ eWih0, const float* __restrict__ eWhh0,
    const float* __restrict__ eWih1, const float* __restrict__ eWhh1,
    const float* __restrict__ dWih0, const float* __restrict__ dWhh0,
    const float* __restrict__ dWih1, const float* __restrict__ dWhh1,
    const float* __restrict__ ebi0, const float* __restrict__ ebh0,
    const float* __restrict__ ebi1, const float* __restrict__ ebh1,
    const float* __restrict__ dbi0, const float* __restrict__ dbh0,
    const float* __restrict__ dbi1, const float* __restrict__ dbh1,
    __half* __restrict__ hE0,   // 257 fresh slots (encoder h0)
    __half* __restrict__ hD0,   // 257 fresh slots (decoder h0)
    __half* __restrict__ h1pp,  // 2-slot ping-pong (h1, both segments)
    __half* __restrict__ femb, float* __restrict__ out,
    unsigned* __restrict__ ctr) {
  extern __shared__ __half lds[];
  const int tid   = threadIdx.x, lane = tid & 63;
  const int mtile = tid >> 6;          // wave id = m-tile (batch rows mtile*16..+16)
  const int layer = blockIdx.x >> 7;
  const int jb    = blockIdx.x & 127;
  const int c4 = lane & 15, kq = lane >> 4;
  const int gi = c4 >> 2;
  const int arow = mtile * 16 + c4;
  unsigned* myctr = ctr + (blockIdx.x & 7) * 16;  // 64B apart
  const int coh1 = (layer == 1);       // s1 coherent only when it's h1 (ping-pong)

  f32x4 cA = {0.f, 0.f, 0.f, 0.f};     // cell state (n=0 tile), regs across enc->dec
  f32x4 cB = {0.f, 0.f, 0.f, 0.f};     // cell state (n=1 tile)
  unsigned tgt = 0;

  for (int seg = 0; seg < 2; ++seg) {
    // ---- stage [32 cols x 2048 K] f16 weights into LDS from the f32 inputs ----
    const float* Wih; const float* Whh; int flip = 0;
    if (seg == 0) { Wih = layer ? eWih1 : eWih0; Whh = layer ? eWhh1 : eWhh0; }
    else { Wih = layer ? dWih1 : dWih0; Whh = layer ? dWhh1 : dWhh0; flip = (layer == 0); }
    const int k0 = tid * 8;
    for (int i = 0; i < 32; ++i) {      // i = LDS column, thread covers K-chunk tid
      int cc4 = i & 15, ct = i >> 4;
      int n = (cc4 >> 2) * 1024 + jb * 8 + ct * 4 + (cc4 & 3);
      half8 t;
      if (k0 < 1024) {
        if (flip) {
          #pragma unroll
          for (int e = 0; e < 8; ++e) t[e] = (_Float16)Wih[(size_t)n * 1024 + 1023 - k0 - e];
        } else {
          #pragma unroll
          for (int e = 0; e < 8; ++e) t[e] = (_Float16)Wih[(size_t)n * 1024 + k0 + e];
        }
      } else {
        #pragma unroll
        for (int e = 0; e < 8; ++e) t[e] = (_Float16)Whh[(size_t)n * 1024 + k0 - 1024 + e];
      }
      *(half8*)(lds + ((size_t)tid * 32 + i) * 8) = t;
    }
    const float* bi = (seg == 0) ? (layer ? ebi1 : ebi0) : (layer ? dbi1 : dbi0);
    const float* bh = (seg == 0) ? (layer ? ebh1 : ebh0) : (layer ? dbh1 : dbh0);
    const int nl0 = gi * 1024 + jb * 8 + (lane & 3);
    const float bb0 = bi[nl0] + bh[nl0];
    const float bb1 = bi[nl0 + 4] + bh[nl0 + 4];
    __syncthreads();
    asm volatile("s_waitcnt vmcnt(0)" ::: "memory");  // clean vmcnt before counted phases

    const __half* ldsb = lds + ((size_t)kq * 32 + c4) * 8;
    __half* h0b = seg ? hD0 : hE0;

    for (int p = 0; p <= 256; ++p) {
      // h0: fresh linear slots (write p+1, read p); dec p=0 recurrent = hE0[256].
      // h1: 2-slot ping-pong shared across segments (write p&1, read (p+1)&1);
      //     dec p=1 naturally reads hE... h1pp[0] = encoder-final h1 (written enc p=256).
      const __half* l0rec = (seg && p == 0) ? hE0 + (size_t)256 * HS
                                            : h0b + (size_t)p * HS;
      __half*       l0wr  = h0b + (size_t)(p + 1) * HS;
      const __half* l1in  = h0b + (size_t)p * HS;
      const __half* l1rec = h1pp + (size_t)((p + 1) & 1) * HS;
      __half*       l1wr  = h1pp + (size_t)(p & 1) * HS;

      const int active = (layer == 0) ? (p <= 255) : (p >= 1);
      if (active) {
        const __half* s1 = (layer == 0) ? l0rec : l1rec;
        const __half* s0;
        long long st0;
        if (layer == 0) {
          if (seg == 0)      { s0 = xf16 + (size_t)p * 1024;       st0 = 262144; }
          else if (p == 0)   { s0 = femb;                          st0 = 1024;   }
          else               { s0 = xf16 + (size_t)(p - 1) * 1024; st0 = 262144; }
        } else             { s0 = l1in;                            st0 = 1024;   }

        const __half* pa = s0 + (long long)arow * st0 + kq * 8;
        const __half* pb = s1 + (long long)arow * 1024 + kq * 8;
        f32x4 accA = {0.f, 0.f, 0.f, 0.f};
        f32x4 accB = {0.f, 0.f, 0.f, 0.f};
        half8 A0,A1,A2,A3,A4,A5,A6,A7, B0,B1,B2,B3,B4,B5,B6,B7,
              C0,C1,C2,C3,C4,C5,C6,C7, D0,D1,D2,D3,D4,D5,D6,D7;

        // 8 chunks (0-3: s0, 4-7: s1), 4 banks in flight, counted vmcnt
        ISSUE(A, 0); ISSUE(B, 1); ISSUE(C, 2); ISSUE(D, 3);
        WAITVM(24); MFMA16(A, 0); ISSUE(A, 4);
        WAITVM(24); MFMA16(B, 1); ISSUE(B, 5);
        WAITVM(24); MFMA16(C, 2); ISSUE(C, 6);
        WAITVM(24); MFMA16(D, 3); ISSUE(D, 7);
        WAITVM(24); MFMA16(A, 4);
        WAITVM(16); MFMA16(B, 5);
        WAITVM(8);  MFMA16(C, 6);
        WAITVM(0);  MFMA16(D, 7);

        __half* hdst = (layer == 0) ? l0wr : l1wr;
        EPI(accA, cA, bb0, 0);
        EPI(accB, cB, bb1, 1);
      }

      // ---- grid barrier: drain coherent stores, arrive on spread counters, poll ----
      tgt += NBLK;
      asm volatile("s_waitcnt vmcnt(0)" ::: "memory");
      __syncthreads();
      if (tid == 0) {
        __hip_atomic_fetch_add(myctr, 1u, __ATOMIC_RELAXED, __HIP_MEMORY_SCOPE_AGENT);
        int guard = 0;
        while (poll8(ctr) < tgt) {
          __builtin_amdgcn_s_sleep(1);
          if (++guard > (1 << 18)) break;  // hang safety: break (wrong results, no hang)
        }
      }
      __syncthreads();
    }
  }
}

extern "C" void kernel_launch(void* const* d_in, const int* in_sizes, int n_in,
                              void* d_out, int out_size, void* d_ws, size_t ws_size,
                              hipStream_t stream) {
  const float* x     = (const float*)d_in[0];
  const float* eWih0 = (const float*)d_in[1];
  const float* eWhh0 = (const float*)d_in[2];
  const float* ebih0 = (const float*)d_in[3];
  const float* ebhh0 = (const float*)d_in[4];
  const float* eWih1 = (const float*)d_in[5];
  const float* eWhh1 = (const float*)d_in[6];
  const float* ebih1 = (const float*)d_in[7];
  const float* ebhh1 = (const float*)d_in[8];
  const float* dWih0 = (const float*)d_in[9];
  const float* dWhh0 = (const float*)d_in[10];
  const float* dbih0 = (const float*)d_in[11];
  const float* dbhh0 = (const float*)d_in[12];
  const float* dWih1 = (const float*)d_in[13];
  const float* dWhh1 = (const float*)d_in[14];
  const float* dbih1 = (const float*)d_in[15];
  const float* dbhh1 = (const float*)d_in[16];
  float* out = (float*)d_out;

  char* ws = (char*)d_ws;
  size_t off = 0;
  auto alloc = [&](size_t bytes) { char* p = ws + off; off += (bytes + 255) & ~(size_t)255; return p; };
  const size_t SLOT = (size_t)HS * sizeof(__half);            // 128KB
  __half* xf16 = (__half*)alloc((size_t)64 * 256 * 1024 * sizeof(__half));  // 32MB
  __half* hE0  = (__half*)alloc(257 * SLOT);                  // 32.1MB fresh slots
  __half* hD0  = (__half*)alloc(257 * SLOT);                  // 32.1MB fresh slots
  __half* h1pp = (__half*)alloc(2 * SLOT);                    // ping-pong (coherent)
  __half* femb = (__half*)alloc(SLOT);
  unsigned* ctr = (unsigned*)alloc(1024);

  if (ws_size < off) {  // loud failure: absmax == ws_size in MB * 1e6
    hipLaunchKernelGGL(fail_mark, dim3(1), dim3(1), 0, stream,
                       out, (float)(ws_size >> 20));
    return;
  }

  const int xn = 64 * 256 * 1024;
  cvt_x<<<(xn + 255) / 256, 256, 0, stream>>>(x, xf16, xn);

  hipMemsetAsync(hE0, 0, SLOT, stream);   // h0 slot0 = zeros
  hipMemsetAsync(h1pp, 0, SLOT, stream);  // h1 slot0 = zeros (read at enc p=1)
  hipMemsetAsync(ctr, 0, 1024, stream);

  hipFuncSetAttribute((const void*)lstm_persist,
                      hipFuncAttributeMaxDynamicSharedMemorySize, LDS_BYTES);
  lstm_persist<<<NBLK, NTHR, LDS_BYTES, stream>>>(
      xf16,
      eWih0, eWhh0, eWih1, eWhh1, dWih0, dWhh0, dWih1, dWhh1,
      ebih0, ebhh0, ebih1, ebhh1, dbih0, dbhh0, dbih1, dbhh1,
      hE0, hD0, h1pp, femb, out, ctr);
}